// Round 5
// baseline (406.297 us; speedup 1.0000x reference)
//
#include <hip/hip_runtime.h>
#include <math.h>

// Problem constants (fixed by the reference file)
#define T_ 256
#define N_ 64
#define C_ 4096
#define L_ 32
#define SL_ 33            // compact slots per (n,t): 0 = blank, 1+l = label l
#define NBLK (T_ * N_ / 4)   // 4096 blocks, 4 rows each

// whole-wave shift-toward-higher-lane by 1 via DPP (wave_shr:1 = 0x138).
__device__ __forceinline__ float dpp_shr1(float x, float fill) {
    int r = __builtin_amdgcn_update_dpp(__float_as_int(fill), __float_as_int(x),
                                        0x138, 0xF, 0xF, false);
    return __int_as_float(r);
}

#define DPP_FMAX(v, ctrl) \
    fmaxf((v), __int_as_float(__builtin_amdgcn_update_dpp( \
        __float_as_int(v), __float_as_int(v), (ctrl), 0xF, 0xF, false)))

__device__ __forceinline__ float wred_max(float v) {
    #pragma unroll
    for (int o = 32; o > 0; o >>= 1) v = fmaxf(v, __shfl_xor(v, o));
    return v;
}
__device__ __forceinline__ float wred_sum(float v) {
    #pragma unroll
    for (int o = 32; o > 0; o >>= 1) v += __shfl_xor(v, o);
    return v;
}

// Write-through store to the device coherence point (L3). sc0 sc1 bypasses
// the non-coherent XCD L2 so a consumer block on another XCD can read the
// value after a vmcnt(0)-ordered ticket release, without any wbl2 flush.
__device__ __forceinline__ void store_agent_f32(float* p, float v) {
    asm volatile("global_store_dword %0, %1, off sc0 sc1"
                 :: "v"(p), "v"(v) : "memory");
}

// Fused kernel. Phase A (all 4096 blocks): softmax rows, math identical to
// the verified k_row_lse; pmat stored with sc1 write-through. Ticket via
// device-scope atomicAdd after a per-wave vmcnt(0) drain + block barrier.
// Phase B (tickets 4032..4095, i.e. the last 64 arrivals): spin until all
// 4096 blocks have released, acquire-fence, then run the verified R6 scan
// for batch item myn = ticket-4032. The counter keeps counting for the
// final partial[] mean-reduction (done == NBLK+N_-1 selects the last).
__global__ __launch_bounds__(256) void k_fused(
        const float* __restrict__ preds, const int* __restrict__ targets,
        const int* __restrict__ plen, const int* __restrict__ tlen,
        float* __restrict__ pmat, float* __restrict__ partial,
        int* counter, float* __restrict__ out) {
    // Pad: deepest scan prefetch index is (249+8+7)*SL_+32 = 8744;
    // (T_+16)*SL_ = 8976 covers it.  35.9 KB -> 4 blocks/CU (BW still
    // saturated in phase A: 16 waves/CU x 16KB outstanding >> 10KB needed).
    __shared__ __align__(16) float lds[(T_ + 16) * SL_];
    __shared__ int s_ticket;

    // ---------------- Phase A: one wave per (t,n) row ----------------
    const int wv     = threadIdx.x >> 6;
    const int lane   = threadIdx.x & 63;
    const int row_id = (blockIdx.x << 2) | wv;      // row_id = t*N_ + n
    const int n = row_id & (N_ - 1);
    const float* row = preds + (size_t)row_id * C_;

    float gv = 0.f;
    if (lane < SL_) {
        const int cls = (lane == 0) ? 0 : targets[n * L_ + (lane - 1)];
        gv = row[cls];
    }

    float4 v[16];
    #pragma unroll
    for (int k = 0; k < 16; ++k) v[k] = ((const float4*)row)[lane + (k << 6)];

    float m = v[0].x;
    #pragma unroll
    for (int k = 0; k < 16; ++k)
        m = fmaxf(m, fmaxf(fmaxf(v[k].x, v[k].y), fmaxf(v[k].z, v[k].w)));
    m = wred_max(m);

    float s = 0.f;
    #pragma unroll
    for (int k = 0; k < 16; ++k)
        s += __expf(v[k].x - m) + __expf(v[k].y - m)
           + __expf(v[k].z - m) + __expf(v[k].w - m);
    s = wred_sum(s);
    const float lse = m + __logf(s);

    if (lane < SL_) {
        const int t = row_id >> 6;
        store_agent_f32(&pmat[((size_t)n * T_ + t) * SL_ + lane],
                        __expf(gv - lse));
    }

    // ---------------- Ticket release ----------------
    // Each wave drains its sc1 stores (acked at L3), barrier joins all 4
    // waves, then one device-scope RMW publishes this block's completion.
    asm volatile("s_waitcnt vmcnt(0)" ::: "memory");
    __syncthreads();
    if (threadIdx.x == 0) s_ticket = atomicAdd(counter, 1);
    __syncthreads();
    const int ticket = s_ticket;
    if (ticket < NBLK - N_) return;         // 4032 blocks done

    // ---------------- Phase B: CTC scan for myn ----------------
    const int myn = ticket - (NBLK - N_);
    const int tl = tlen[myn];
    const int pl = plen[myn];

    if (threadIdx.x == 0) {
        while (__hip_atomic_load(counter, __ATOMIC_RELAXED,
                                 __HIP_MEMORY_SCOPE_AGENT) < NBLK)
            __builtin_amdgcn_s_sleep(1);
    }
    __syncthreads();
    __threadfence();    // acquire: invalidate this XCD's L2 (stale poison)

    const float4* src = (const float4*)(pmat + (size_t)myn * T_ * SL_);
    float4* dst4 = (float4*)lds;
    for (int i = threadIdx.x; i < (T_ * SL_) / 4; i += 256) dst4[i] = src[i];
    __syncthreads();
    if (threadIdx.x >= 64) return;          // wave 0 scans; no more barriers

    const int sl   = threadIdx.x;           // scan lane
    const int ends = 2 * tl;
    const bool odd = (sl & 1);
    const int slot   = odd ? 1 + (sl >> 1) : 0;
    const int cls    = odd ? targets[myn * L_ + (sl >> 1)] : 0;
    const int clsm2  = (odd && sl >= 2) ? targets[myn * L_ + (sl >> 1) - 1] : 0;
    const bool skip  = odd && (sl >= 2) && (cls != 0) && (cls != clsm2);
    const bool valid   = sl < 2 * tl + 1;
    const bool valid64 = (2 * tl + 1) > 64;

    float A = 0.f, B = 0.f;
    int esum = 0;
    if (sl == 0) A = lds[0];
    if (sl == 1 && tl > 0) A = lds[1];

    float pf_s[8], pf_b[8];
    #pragma unroll
    for (int j = 0; j < 8; ++j) {
        pf_s[j] = valid   ? lds[(1 + j) * SL_ + slot] : 0.f;
        pf_b[j] = valid64 ? lds[(1 + j) * SL_]        : 0.f;
    }

    for (int t = 1; t <= T_; t += 8) {
        #pragma unroll
        for (int j = 0; j < 8; ++j) {
            const float p_s = pf_s[j];
            const float p_b = pf_b[j];
            pf_s[j] = valid   ? lds[(t + 8 + j) * SL_ + slot] : 0.f;
            pf_b[j] = valid64 ? lds[(t + 8 + j) * SL_]        : 0.f;

            const float A2 = dpp_shr1(A, 0.f);
            float A3 = dpp_shr1(A2, 0.f);
            A3 = skip ? A3 : 0.f;
            const float sum3 = (A + A2) + A3;
            const float nA = sum3 * p_s;
            const float nB = (B + A) * p_b;
            if (t + j < pl) { A = nA; B = nB; }
        }
        if (t + 7 < pl) {
            float mx = fmaxf(A, (sl == 63) ? B : 0.f);
            mx = DPP_FMAX(mx, 0x111);      // row_shr:1
            mx = DPP_FMAX(mx, 0x112);      // row_shr:2
            mx = DPP_FMAX(mx, 0x114);      // row_shr:4
            mx = DPP_FMAX(mx, 0x118);      // row_shr:8
            mx = DPP_FMAX(mx, 0x142);      // row_bcast15
            mx = DPP_FMAX(mx, 0x143);      // row_bcast31 -> lane63 = wave max
            const float mxu = __int_as_float(
                __builtin_amdgcn_readlane(__float_as_int(mx), 63));
            if (mxu > 0.f) {
                const int eb = (__float_as_int(mxu) >> 23) & 255;
                const float scale = __int_as_float((254 - eb) << 23);
                A *= scale; B *= scale;
                esum += eb - 127;
            }
        }
    }

    const float a_last = (ends >= 64) ? __shfl(B, 63) : __shfl(A, ends);
    float a_prev = __shfl(A, (ends > 0) ? (ends - 1) : 0);
    if (tl <= 0) a_prev = 0.f;
    float nll = -(__logf(a_last + a_prev) + (float)esum * 0.69314718056f);
    if (!(isfinite(nll) && nll < 1e29f)) nll = 0.f;
    if (sl == 0) partial[myn] = nll / (float)((tl > 0) ? tl : 1);

    // Mean reduction among the 64 scan blocks: counter keeps counting past
    // NBLK; the block observing NBLK+N_-1 is last. Proven fence pattern.
    __threadfence();
    int done = 0;
    if (sl == 0) done = atomicAdd(counter, 1);
    done = __shfl(done, 0);
    if (done == NBLK + N_ - 1) {
        __threadfence();
        float pv = partial[sl];            // lane n reads partial[n]
        pv = wred_sum(pv);
        if (sl == 0) out[0] = pv * (1.0f / (float)N_);
    }
}

extern "C" void kernel_launch(void* const* d_in, const int* in_sizes, int n_in,
                              void* d_out, int out_size, void* d_ws, size_t ws_size,
                              hipStream_t stream) {
    const float* preds   = (const float*)d_in[0];
    const int*   targets = (const int*)d_in[1];
    const int*   plen    = (const int*)d_in[2];
    const int*   tlen    = (const int*)d_in[3];

    float* pmat    = (float*)d_ws;                    // N*T*33 floats = 2.16 MB
    float* partial = pmat + (size_t)N_ * T_ * SL_;    // +64 floats
    int*   counter = (int*)(partial + N_);            // +1 int

    hipMemsetAsync(counter, 0, sizeof(int), stream);  // ws is poisoned each replay
    k_fused<<<NBLK, 256, 0, stream>>>(preds, targets, plen, tlen, pmat,
                                      partial, counter, (float*)d_out);
}

// Round 8
// 379.011 us; speedup vs baseline: 1.0720x; 1.0720x over previous
//
#include <hip/hip_runtime.h>
#include <math.h>

// Problem constants (fixed by the reference file)
#define T_ 256
#define N_ 64
#define C_ 4096
#define L_ 32
#define SL_ 33            // compact slots per (n,t): 0 = blank, 1+l = label l

// whole-wave shift-toward-higher-lane by 1 via DPP (wave_shr:1 = 0x138).
__device__ __forceinline__ float dpp_shr1(float x, float fill) {
    int r = __builtin_amdgcn_update_dpp(__float_as_int(fill), __float_as_int(x),
                                        0x138, 0xF, 0xF, false);
    return __int_as_float(r);
}

#define DPP_FMAX(v, ctrl) \
    fmaxf((v), __int_as_float(__builtin_amdgcn_update_dpp( \
        __float_as_int(v), __float_as_int(v), (ctrl), 0xF, 0xF, false)))

__device__ __forceinline__ float wred_max(float v) {
    #pragma unroll
    for (int o = 32; o > 0; o >>= 1) v = fmaxf(v, __shfl_xor(v, o));
    return v;
}
__device__ __forceinline__ float wred_sum(float v) {
    #pragma unroll
    for (int o = 32; o > 0; o >>= 1) v += __shfl_xor(v, o);
    return v;
}

// Kernel 1, v2 (occupancy rebuild after the R5 fused-kernel diagnosis:
// phase A ran at 10% HBM / 24% occupancy -> latency-bound). One BLOCK per
// (t,n) row: 256 threads x 4 float4 = 4096 floats. Per-thread data = 16
// VGPRs (vs 64 in the wave-per-row version) -> ~40 VGPR total -> 8 blocks/CU
// = 32 waves/CU, 2x the wave-parallelism, 256 KB of loads in flight per CU.
// Two-pass max->sum preserved (same math shape as the verified kernel; only
// cross-wave reduction order differs). Tiny LDS (32 B), two barriers.
__global__ __launch_bounds__(256) void k_row_lse(
        const float* __restrict__ preds, const int* __restrict__ targets,
        float* __restrict__ pmat, int* __restrict__ counter) {
    __shared__ float red[8];
    const int row_id = blockIdx.x;            // row_id = t*N_ + n
    const int tid  = threadIdx.x;
    const int wv   = tid >> 6;
    const int lane = tid & 63;
    if (row_id == 0 && tid == 0) *counter = 0;
    const int n = row_id & (N_ - 1);
    const float* row = preds + (size_t)row_id * C_;

    // Gather loads issued first; independent of the streaming reduction.
    float gv = 0.f;
    if (wv == 0 && lane < SL_) {
        const int cls = (lane == 0) ? 0 : targets[n * L_ + (lane - 1)];
        gv = row[cls];
    }

    // 1024 float4 per row / 256 threads = 4 float4 each, coalesced.
    float4 v[4];
    #pragma unroll
    for (int j = 0; j < 4; ++j) v[j] = ((const float4*)row)[tid + (j << 8)];

    float m = v[0].x;
    #pragma unroll
    for (int j = 0; j < 4; ++j)
        m = fmaxf(m, fmaxf(fmaxf(v[j].x, v[j].y), fmaxf(v[j].z, v[j].w)));
    m = wred_max(m);
    if (lane == 0) red[wv] = m;
    __syncthreads();
    m = fmaxf(fmaxf(red[0], red[1]), fmaxf(red[2], red[3]));  // block max

    float s = 0.f;
    #pragma unroll
    for (int j = 0; j < 4; ++j)
        s += __expf(v[j].x - m) + __expf(v[j].y - m)
           + __expf(v[j].z - m) + __expf(v[j].w - m);
    s = wred_sum(s);
    if (lane == 0) red[4 + wv] = s;
    __syncthreads();
    s = (red[4] + red[5]) + (red[6] + red[7]);                // block sum
    const float lse = m + __logf(s);

    if (wv == 0 && lane < SL_) {
        const int t = row_id >> 6;            // row_id / N_
        pmat[((size_t)n * T_ + t) * SL_ + lane] = __expf(gv - lse);
    }
}

// Kernel 2: linear-domain (Rabiner-scaled) CTC forward — byte-identical to
// the verified R6 version (383.4 µs run): chunk-8 scan, DPP rescale-max,
// exact power-of-2 rescale with integer exponent bookkeeping.
__global__ __launch_bounds__(256) void k_ctc_scan(
        const float* __restrict__ pmat, const int* __restrict__ targets,
        const int* __restrict__ plen, const int* __restrict__ tlen,
        float* __restrict__ partial, int* __restrict__ counter,
        float* __restrict__ out) {
    // Pad: deepest prefetch index is (249+8+7)*SL_+32 = 8744; (T_+16)*SL_ =
    // 8976 covers it.
    __shared__ __align__(16) float lds[(T_ + 16) * SL_];   // 35.9 KB
    const int n = blockIdx.x;
    const int tid = threadIdx.x;
    const float4* src = (const float4*)(pmat + (size_t)n * T_ * SL_);
    float4* dst = (float4*)lds;
    for (int i = tid; i < (T_ * SL_) / 4; i += 256) dst[i] = src[i];
    __syncthreads();
    if (tid >= 64) return;                 // no further barriers

    const int lane = tid;
    const int tl = tlen[n];
    const int pl = plen[n];
    const int ends = 2 * tl;
    const bool odd = (lane & 1);
    const int slot   = odd ? 1 + (lane >> 1) : 0;
    const int cls    = odd ? targets[n * L_ + (lane >> 1)] : 0;
    const int clsm2  = (odd && lane >= 2) ? targets[n * L_ + (lane >> 1) - 1] : 0;
    const bool skip  = odd && (lane >= 2) && (cls != 0) && (cls != clsm2);
    const bool valid   = lane < 2 * tl + 1;
    const bool valid64 = (2 * tl + 1) > 64;    // is state 64 valid

    float A = 0.f, B = 0.f;     // A = alpha[lane], B = alpha[64] (lane 63)
    int esum = 0;               // sum of log2(rescale) as integer (exact)
    if (lane == 0) A = lds[0];
    if (lane == 1 && tl > 0) A = lds[1];

    // Depth-8 register ring; invalid lanes are zeroed at load (off-chain).
    float pf_s[8], pf_b[8];
    #pragma unroll
    for (int j = 0; j < 8; ++j) {
        pf_s[j] = valid   ? lds[(1 + j) * SL_ + slot] : 0.f;
        pf_b[j] = valid64 ? lds[(1 + j) * SL_]        : 0.f;
    }

    for (int t = 1; t <= T_; t += 8) {
        #pragma unroll
        for (int j = 0; j < 8; ++j) {
            const float p_s = pf_s[j];
            const float p_b = pf_b[j];
            pf_s[j] = valid   ? lds[(t + 8 + j) * SL_ + slot] : 0.f;
            pf_b[j] = valid64 ? lds[(t + 8 + j) * SL_]        : 0.f;

            const float A2 = dpp_shr1(A, 0.f);         // alpha[lane-1]
            float A3 = dpp_shr1(A2, 0.f);              // alpha[lane-2]
            A3 = skip ? A3 : 0.f;
            const float sum3 = (A + A2) + A3;
            const float nA = sum3 * p_s;               // p_s==0 if !valid
            const float nB = (B + A) * p_b;            // p_b==0 if !valid64
            if (t + j < pl) { A = nA; B = nB; }        // wave-uniform predicate
        }
        if (t + 7 < pl) {
            float mx = fmaxf(A, (lane == 63) ? B : 0.f);
            mx = DPP_FMAX(mx, 0x111);      // row_shr:1
            mx = DPP_FMAX(mx, 0x112);      // row_shr:2
            mx = DPP_FMAX(mx, 0x114);      // row_shr:4
            mx = DPP_FMAX(mx, 0x118);      // row_shr:8
            mx = DPP_FMAX(mx, 0x142);      // row_bcast15
            mx = DPP_FMAX(mx, 0x143);      // row_bcast31 -> lane63 = wave max
            const float mxu = __int_as_float(
                __builtin_amdgcn_readlane(__float_as_int(mx), 63));
            if (mxu > 0.f) {
                const int eb = (__float_as_int(mxu) >> 23) & 255;
                const float scale = __int_as_float((254 - eb) << 23); // 2^(127-eb)
                A *= scale; B *= scale;    // exact
                esum += eb - 127;          // exact log2 bookkeeping
            }
        }
    }

    const float a_last = (ends >= 64) ? __shfl(B, 63) : __shfl(A, ends);
    float a_prev = __shfl(A, (ends > 0) ? (ends - 1) : 0);
    if (tl <= 0) a_prev = 0.f;
    float nll = -(__logf(a_last + a_prev) + (float)esum * 0.69314718056f);
    if (!(isfinite(nll) && nll < 1e29f)) nll = 0.f;
    if (lane == 0) partial[n] = nll / (float)((tl > 0) ? tl : 1);

    // Last-block-done mean reduction (proven pattern).
    __threadfence();
    int done = 0;
    if (lane == 0) done = atomicAdd(counter, 1);
    done = __shfl(done, 0);
    if (done == N_ - 1) {
        __threadfence();
        float v = partial[lane];               // lane n reads partial[n]
        v = wred_sum(v);
        if (lane == 0) out[0] = v * (1.0f / (float)N_);
    }
}

extern "C" void kernel_launch(void* const* d_in, const int* in_sizes, int n_in,
                              void* d_out, int out_size, void* d_ws, size_t ws_size,
                              hipStream_t stream) {
    const float* preds   = (const float*)d_in[0];
    const int*   targets = (const int*)d_in[1];
    const int*   plen    = (const int*)d_in[2];
    const int*   tlen    = (const int*)d_in[3];

    float* pmat    = (float*)d_ws;                    // N*T*33 floats = 2.16 MB
    float* partial = pmat + (size_t)N_ * T_ * SL_;    // +64 floats
    int*   counter = (int*)(partial + N_);            // +1 int

    k_row_lse<<<T_ * N_, 256, 0, stream>>>(preds, targets, pmat, counter);
    k_ctc_scan<<<N_, 256, 0, stream>>>(pmat, targets, plen, tlen, partial,
                                       counter, (float*)d_out);
}